// Round 1
// baseline (1151.717 us; speedup 1.0000x reference)
//
#include <hip/hip_runtime.h>
#include <hip/hip_bf16.h>

#define N_NODES 50000
#define M_PAD   50048   /* 391 * 128 */
#define MT_     391
#define F_IN    768
#define PROJ    1024
#define HID     256
#define OUTD    128
#define E_WB    200000
#define E_MB    200000
#define E_INT   500000
#define KPB     4

typedef float f32x4 __attribute__((ext_vector_type(4)));
typedef __bf16 bf16x8 __attribute__((ext_vector_type(8)));

__device__ __forceinline__ float bf2f(unsigned short u) {
  union { unsigned int i; float f; } x; x.i = ((unsigned int)u) << 16; return x.f;
}
__device__ __forceinline__ unsigned short f2bf(float f) {
  union { float f; unsigned int i; } x; x.f = f;
  unsigned int r = x.i + 0x7fff + ((x.i >> 16) & 1);
  return (unsigned short)(r >> 16);
}

// ---------------- weight fusion: Ff[k][j] = sum_p W1[k][p] * [Wl1|Wl2][p][j] ----------------
__global__ void fuse_f_kernel(const float* __restrict__ W1, const float* __restrict__ Wl1,
                              const float* __restrict__ Wl2, float* __restrict__ Ff) {
  int j = threadIdx.x;                 // 512
  int k0 = blockIdx.x * KPB;
  const float* wl = (j < HID) ? (Wl1 + j) : (Wl2 + (j - HID));
  float acc[KPB];
#pragma unroll
  for (int kk = 0; kk < KPB; ++kk) acc[kk] = 0.f;
  for (int p = 0; p < PROJ; ++p) {
    float w = wl[p * HID];
#pragma unroll
    for (int kk = 0; kk < KPB; ++kk) acc[kk] += W1[(k0 + kk) * PROJ + p] * w;
  }
#pragma unroll
  for (int kk = 0; kk < KPB; ++kk) Ff[(k0 + kk) * 512 + j] = acc[kk];
}

// Gf[k][j] = j<256 ? sum_p W2[k][p]*Wr1[p][j]  :  Wr3[k][j-256]
__global__ void fuse_g_kernel(const float* __restrict__ W2, const float* __restrict__ Wr1,
                              const float* __restrict__ Wr3, float* __restrict__ Gf) {
  int j = threadIdx.x;
  int k0 = blockIdx.x * KPB;
  if (j < HID) {
    float acc[KPB];
#pragma unroll
    for (int kk = 0; kk < KPB; ++kk) acc[kk] = 0.f;
    for (int p = 0; p < PROJ; ++p) {
      float w = Wr1[p * HID + j];
#pragma unroll
      for (int kk = 0; kk < KPB; ++kk) acc[kk] += W2[(k0 + kk) * PROJ + p] * w;
    }
#pragma unroll
    for (int kk = 0; kk < KPB; ++kk) Gf[(k0 + kk) * 512 + j] = acc[kk];
  } else {
#pragma unroll
    for (int kk = 0; kk < KPB; ++kk) Gf[(k0 + kk) * 512 + j] = Wr3[(k0 + kk) * HID + (j - HID)];
  }
}

// gb1 = b1@Wl1, gb2 = b1@Wl2, bv1 = bl1 + b2@Wr1   (all [256])
__global__ void bias_prep_kernel(const float* __restrict__ b1, const float* __restrict__ b2,
                                 const float* __restrict__ bl1,
                                 const float* __restrict__ Wl1, const float* __restrict__ Wl2,
                                 const float* __restrict__ Wr1,
                                 float* __restrict__ gb1, float* __restrict__ gb2,
                                 float* __restrict__ bv1) {
  int j = threadIdx.x;  // 256
  float s1 = 0.f, s2 = 0.f, s3 = 0.f;
  for (int p = 0; p < PROJ; ++p) {
    float a = b1[p], b = b2[p];
    s1 += a * Wl1[p * HID + j];
    s2 += a * Wl2[p * HID + j];
    s3 += b * Wr1[p * HID + j];
  }
  gb1[j] = s1; gb2[j] = s2; bv1[j] = bl1[j] + s3;
}

// transpose + cast fp32 [R][C] -> bf16 [C][R]
__global__ void tcast_kernel(const float* __restrict__ src, unsigned short* __restrict__ dst,
                             int R, int C) {
  __shared__ float tile[32][33];
  int x = blockIdx.x * 32 + threadIdx.x;
  int y0 = blockIdx.y * 32;
  for (int i = threadIdx.y; i < 32; i += blockDim.y)
    tile[i][threadIdx.x] = src[(long long)(y0 + i) * C + x];
  __syncthreads();
  int xo = blockIdx.y * 32 + threadIdx.x;
  int yo0 = blockIdx.x * 32;
  for (int i = threadIdx.y; i < 32; i += blockDim.y)
    dst[(long long)(yo0 + i) * R + xo] = f2bf(tile[threadIdx.x][i]);
}

// fp32 [rows_valid][cols] -> bf16 [rows_pad][cols], pad rows zeroed. one 16B chunk / thread
__global__ void cast_pad_kernel(const float* __restrict__ src, unsigned short* __restrict__ dst,
                                int rows_valid, long long total_chunks, int cpr) {
  long long i = (long long)blockIdx.x * 256 + threadIdx.x;
  if (i >= total_chunks) return;
  int row = (int)(i / cpr);
  int c8 = (int)(i % cpr);
  uint4 o;
  if (row < rows_valid) {
    const float4* s4 = (const float4*)src;
    long long base = (long long)row * (cpr * 2) + c8 * 2;
    float4 a = s4[base], b = s4[base + 1];
    o.x = (unsigned int)f2bf(a.x) | ((unsigned int)f2bf(a.y) << 16);
    o.y = (unsigned int)f2bf(a.z) | ((unsigned int)f2bf(a.w) << 16);
    o.z = (unsigned int)f2bf(b.x) | ((unsigned int)f2bf(b.y) << 16);
    o.w = (unsigned int)f2bf(b.z) | ((unsigned int)f2bf(b.w) << 16);
  } else {
    o.x = o.y = o.z = o.w = 0u;
  }
  ((uint4*)dst)[i] = o;
}

// ---------------- CSR build ----------------
__global__ void count_all_kernel(const int* __restrict__ dwb, const int* __restrict__ dmb,
                                 const int* __restrict__ dint,
                                 int* __restrict__ cwb, int* __restrict__ cmb,
                                 int* __restrict__ cint) {
  int i = blockIdx.x * blockDim.x + threadIdx.x;
  const int total = E_WB + E_MB + E_INT;
  if (i >= total) return;
  if (i < E_WB) atomicAdd(&cwb[dwb[i]], 1);
  else if (i < E_WB + E_MB) atomicAdd(&cmb[dmb[i - E_WB]], 1);
  else atomicAdd(&cint[dint[i - E_WB - E_MB]], 1);
}

__global__ void scan3_kernel(const int* __restrict__ c0, const int* __restrict__ c1,
                             const int* __restrict__ c2,
                             int* __restrict__ o0, int* __restrict__ o1, int* __restrict__ o2) {
  const int* cnt = blockIdx.x == 0 ? c0 : (blockIdx.x == 1 ? c1 : c2);
  int* off = blockIdx.x == 0 ? o0 : (blockIdx.x == 1 ? o1 : o2);
  const int n = N_NODES;
  __shared__ int part[1024];
  int t = threadIdx.x;
  const int chunk = (n + 1023) / 1024;
  int lo = t * chunk, hi = lo + chunk; if (hi > n) hi = n; if (lo > n) lo = n;
  int s = 0;
  for (int i = lo; i < hi; ++i) s += cnt[i];
  part[t] = s; __syncthreads();
  for (int d = 1; d < 1024; d <<= 1) {
    int v = part[t];
    if (t >= d) v += part[t - d];
    __syncthreads();
    part[t] = v;
    __syncthreads();
  }
  int run = (t == 0) ? 0 : part[t - 1];
  for (int i = lo; i < hi; ++i) { off[i] = run; run += cnt[i]; }
  if (t == 1023) off[n] = part[1023];
}

__global__ void fill_all_kernel(const int* __restrict__ ewb, const int* __restrict__ emb,
                                const int* __restrict__ eint,
                                const int* __restrict__ owb, const int* __restrict__ omb,
                                const int* __restrict__ oint,
                                int* __restrict__ curwb, int* __restrict__ curmb,
                                int* __restrict__ curint,
                                int* __restrict__ swb, int* __restrict__ smb,
                                int* __restrict__ sint) {
  int i = blockIdx.x * blockDim.x + threadIdx.x;
  const int total = E_WB + E_MB + E_INT;
  if (i >= total) return;
  if (i < E_WB) {
    int s = ewb[i], d = ewb[E_WB + i];
    int p = atomicAdd(&curwb[d], 1);
    swb[owb[d] + p] = s;
  } else if (i < E_WB + E_MB) {
    int e = i - E_WB;
    int s = emb[e], d = emb[E_MB + e];
    int p = atomicAdd(&curmb[d], 1);
    smb[omb[d] + p] = s;
  } else {
    int e = i - E_WB - E_MB;
    int s = eint[e], d = eint[E_INT + e];
    int p = atomicAdd(&curint[d], 1);
    sint[oint[d] + p] = s;
  }
}

// ---------------- GEMM: C[M][N] = A[M_PAD][K](bf16) * BT[N][K](bf16)^T ----------------
// EPI 0: store bf16.  EPI 1: relu(acc + bias[c] + bf2f(addm[r*as+c])) -> bf16 (conv3 epilogue)
// EPI 2: acc + bias[c] -> fp32 (final lin3)
template <int EPI>
__global__ void __launch_bounds__(256, 2)
gemm_bt_kernel(const unsigned short* __restrict__ A, const unsigned short* __restrict__ BT,
               void* __restrict__ Cv, int K, int N, int Mvalid,
               const float* __restrict__ bias, const unsigned short* __restrict__ addm,
               int addm_stride) {
  __shared__ __align__(16) unsigned short lA[128 * 32];
  __shared__ __align__(16) unsigned short lB[128 * 32];
  const int tid = threadIdx.x;
  const int lane = tid & 63;
  const int wave = tid >> 6;
  const int NT = N >> 7;
  const int mt = blockIdx.x / NT;
  const int nt = blockIdx.x % NT;
  const int m0 = mt * 128, n0 = nt * 128;
  const int wm = (wave & 1) * 64, wn = (wave >> 1) * 64;

  f32x4 acc[4][4];
#pragma unroll
  for (int i = 0; i < 4; ++i)
#pragma unroll
    for (int j = 0; j < 4; ++j)
#pragma unroll
      for (int r = 0; r < 4; ++r) acc[i][j][r] = 0.f;

  const int r0 = tid >> 2;
  const int c0 = (tid & 3) * 8;     // element offset in K within tile
  const uint4* A4 = (const uint4*)A;
  const uint4* B4 = (const uint4*)BT;
  const int K8 = K >> 3;
  const int mrow = lane & 15, kq = lane >> 4;

  for (int kt = 0; kt < K; kt += 32) {
    const int kc = (kt + c0) >> 3;
    uint4 a0 = A4[(long long)(m0 + r0) * K8 + kc];
    uint4 a1 = A4[(long long)(m0 + 64 + r0) * K8 + kc];
    uint4 b0 = B4[(long long)(n0 + r0) * K8 + kc];
    uint4 b1 = B4[(long long)(n0 + 64 + r0) * K8 + kc];
    __syncthreads();
    *(uint4*)&lA[r0 * 32 + c0] = a0;
    *(uint4*)&lA[(64 + r0) * 32 + c0] = a1;
    *(uint4*)&lB[r0 * 32 + c0] = b0;
    *(uint4*)&lB[(64 + r0) * 32 + c0] = b1;
    __syncthreads();
    bf16x8 af[4], bfr[4];
#pragma unroll
    for (int i = 0; i < 4; ++i) af[i] = *(const bf16x8*)&lA[(wm + i * 16 + mrow) * 32 + kq * 8];
#pragma unroll
    for (int j = 0; j < 4; ++j) bfr[j] = *(const bf16x8*)&lB[(wn + j * 16 + mrow) * 32 + kq * 8];
#pragma unroll
    for (int i = 0; i < 4; ++i)
#pragma unroll
      for (int j = 0; j < 4; ++j)
        acc[i][j] = __builtin_amdgcn_mfma_f32_16x16x32_bf16(af[i], bfr[j], acc[i][j], 0, 0, 0);
  }

  const int col_l = lane & 15, rq = lane >> 4;
#pragma unroll
  for (int i = 0; i < 4; ++i) {
#pragma unroll
    for (int j = 0; j < 4; ++j) {
#pragma unroll
      for (int r = 0; r < 4; ++r) {
        int R = m0 + wm + i * 16 + rq * 4 + r;
        int Cc = n0 + wn + j * 16 + col_l;
        if (R < Mvalid) {
          float v = acc[i][j][r];
          if constexpr (EPI == 0) {
            ((unsigned short*)Cv)[(long long)R * N + Cc] = f2bf(v);
          } else if constexpr (EPI == 1) {
            v += bias[Cc] + bf2f(addm[(long long)R * addm_stride + Cc]);
            v = v > 0.f ? v : 0.f;
            ((unsigned short*)Cv)[(long long)R * N + Cc] = f2bf(v);
          } else {
            ((float*)Cv)[(long long)R * N + Cc] = v + bias[Cc];
          }
        }
      }
    }
  }
}

// ---------------- aggregation: one wave per dst row, 4 cols per lane ----------------
// MODE 0/1: out = relu(mean + [deg>0]*gb[c] + bvec[c] + bf2f(addm[d*as+c]))  -> bf16
// MODE 2:   out = bf16(mean)
template <int MODE>
__global__ void agg_kernel(const unsigned short* __restrict__ S, int s_stride,
                           const int* __restrict__ off, const int* __restrict__ srcl,
                           const float* __restrict__ gb, const float* __restrict__ bvec,
                           const unsigned short* __restrict__ addm, int a_stride,
                           unsigned short* __restrict__ out) {
  int d = blockIdx.x;
  int c = threadIdx.x * 4;
  if (d >= N_NODES) {
    ushort4 z; z.x = z.y = z.z = z.w = 0;
    *(ushort4*)&out[(long long)d * HID + c] = z;
    return;
  }
  int lo = off[d], hi = off[d + 1];
  float s0 = 0.f, s1 = 0.f, s2 = 0.f, s3 = 0.f;
  for (int i = lo; i < hi; ++i) {
    int sidx = srcl[i];
    uint2 v = *(const uint2*)&S[(long long)sidx * s_stride + c];
    s0 += bf2f((unsigned short)(v.x & 0xffff));
    s1 += bf2f((unsigned short)(v.x >> 16));
    s2 += bf2f((unsigned short)(v.y & 0xffff));
    s3 += bf2f((unsigned short)(v.y >> 16));
  }
  int deg = hi - lo;
  float inv = deg > 0 ? 1.f / (float)deg : 0.f;
  float v0 = s0 * inv, v1 = s1 * inv, v2 = s2 * inv, v3 = s3 * inv;
  if constexpr (MODE != 2) {
    float g = deg > 0 ? 1.f : 0.f;
    uint2 am = *(const uint2*)&addm[(long long)d * a_stride + c];
    v0 += g * gb[c] + bvec[c] + bf2f((unsigned short)(am.x & 0xffff));
    v1 += g * gb[c + 1] + bvec[c + 1] + bf2f((unsigned short)(am.x >> 16));
    v2 += g * gb[c + 2] + bvec[c + 2] + bf2f((unsigned short)(am.y & 0xffff));
    v3 += g * gb[c + 3] + bvec[c + 3] + bf2f((unsigned short)(am.y >> 16));
    v0 = fmaxf(v0, 0.f); v1 = fmaxf(v1, 0.f); v2 = fmaxf(v2, 0.f); v3 = fmaxf(v3, 0.f);
  }
  ushort4 o;
  o.x = f2bf(v0); o.y = f2bf(v1); o.z = f2bf(v2); o.w = f2bf(v3);
  *(ushort4*)&out[(long long)d * HID + c] = o;
}

extern "C" void kernel_launch(void* const* d_in, const int* in_sizes, int n_in,
                              void* d_out, int out_size, void* d_ws, size_t ws_size,
                              hipStream_t stream) {
  const float* article_x = (const float*)d_in[0];
  const float* community_x = (const float*)d_in[1];
  const int* e_wb = (const int*)d_in[2];
  const int* e_mb = (const int*)d_in[3];
  const int* e_int = (const int*)d_in[4];
  const float* W1 = (const float*)d_in[5];
  const float* b1 = (const float*)d_in[6];
  const float* W2 = (const float*)d_in[7];
  const float* b2 = (const float*)d_in[8];
  const float* Wl1 = (const float*)d_in[9];
  const float* bl1 = (const float*)d_in[10];
  const float* Wr1 = (const float*)d_in[11];
  const float* Wl2 = (const float*)d_in[12];
  const float* bl2 = (const float*)d_in[13];
  const float* Wr2 = (const float*)d_in[14];
  const float* Wl3 = (const float*)d_in[15];
  const float* bl3 = (const float*)d_in[16];
  const float* Wr3 = (const float*)d_in[17];
  const float* W3 = (const float*)d_in[18];
  const float* b3 = (const float*)d_in[19];

  char* base = (char*)d_ws;
  size_t off = 0;
  auto alloc = [&](size_t bytes) -> void* {
    void* r = base + off;
    off += (bytes + 255) & ~(size_t)255;
    return r;
  };

  unsigned short* Xa = (unsigned short*)alloc((size_t)M_PAD * F_IN * 2);
  unsigned short* Xc = (unsigned short*)alloc((size_t)M_PAD * F_IN * 2);
  unsigned short* AP = (unsigned short*)alloc((size_t)M_PAD * 512 * 2);
  unsigned short* CR = (unsigned short*)alloc((size_t)M_PAD * 512 * 2);
  unsigned short* h1bf = (unsigned short*)alloc((size_t)M_PAD * HID * 2);
  unsigned short* HR2 = (unsigned short*)alloc((size_t)M_PAD * HID * 2);
  unsigned short* h2bf = (unsigned short*)alloc((size_t)M_PAD * HID * 2);
  unsigned short* mean3bf = (unsigned short*)alloc((size_t)M_PAD * HID * 2);
  unsigned short* h3bf = (unsigned short*)alloc((size_t)M_PAD * HID * 2);
  float* Ff = (float*)alloc((size_t)F_IN * 512 * 4);
  float* Gf = (float*)alloc((size_t)F_IN * 512 * 4);
  unsigned short* F12T = (unsigned short*)alloc((size_t)512 * F_IN * 2);
  unsigned short* GT = (unsigned short*)alloc((size_t)512 * F_IN * 2);
  unsigned short* Wr2T = (unsigned short*)alloc((size_t)HID * HID * 2);
  unsigned short* Wl3T = (unsigned short*)alloc((size_t)HID * HID * 2);
  unsigned short* W3T = (unsigned short*)alloc((size_t)OUTD * HID * 2);
  float* gb1 = (float*)alloc(HID * 4);
  float* gb2 = (float*)alloc(HID * 4);
  float* bv1 = (float*)alloc(HID * 4);
  int* ints_base = (int*)alloc((size_t)6 * N_NODES * 4);  // cnt_wb,cur_wb,cnt_mb,cur_mb,cnt_int,cur_int
  int* cnt_wb = ints_base;
  int* cur_wb = ints_base + N_NODES;
  int* cnt_mb = ints_base + 2 * N_NODES;
  int* cur_mb = ints_base + 3 * N_NODES;
  int* cnt_int = ints_base + 4 * N_NODES;
  int* cur_int = ints_base + 5 * N_NODES;
  int* off_wb = (int*)alloc((size_t)(N_NODES + 1) * 4);
  int* off_mb = (int*)alloc((size_t)(N_NODES + 1) * 4);
  int* off_int = (int*)alloc((size_t)(N_NODES + 1) * 4);
  int* srcl_wb = (int*)alloc((size_t)E_WB * 4);
  int* srcl_mb = (int*)alloc((size_t)E_MB * 4);
  int* srcl_int = (int*)alloc((size_t)E_INT * 4);

  // 1. zero the histogram/cursor region
  hipMemsetAsync(ints_base, 0, (size_t)6 * N_NODES * 4, stream);

  // 2. weight fusion + transposes + bias prep
  fuse_f_kernel<<<F_IN / KPB, 512, 0, stream>>>(W1, Wl1, Wl2, Ff);
  fuse_g_kernel<<<F_IN / KPB, 512, 0, stream>>>(W2, Wr1, Wr3, Gf);
  tcast_kernel<<<dim3(512 / 32, F_IN / 32), dim3(32, 8), 0, stream>>>(Ff, F12T, F_IN, 512);
  tcast_kernel<<<dim3(512 / 32, F_IN / 32), dim3(32, 8), 0, stream>>>(Gf, GT, F_IN, 512);
  tcast_kernel<<<dim3(8, 8), dim3(32, 8), 0, stream>>>(Wr2, Wr2T, HID, HID);
  tcast_kernel<<<dim3(8, 8), dim3(32, 8), 0, stream>>>(Wl3, Wl3T, HID, HID);
  tcast_kernel<<<dim3(4, 8), dim3(32, 8), 0, stream>>>(W3, W3T, HID, OUTD);
  bias_prep_kernel<<<1, 256, 0, stream>>>(b1, b2, bl1, Wl1, Wl2, Wr1, gb1, gb2, bv1);

  // 3. cast node features to bf16 (zero-padded to M_PAD rows)
  long long tc = (long long)M_PAD * (F_IN / 8);
  cast_pad_kernel<<<(unsigned)((tc + 255) / 256), 256, 0, stream>>>(article_x, Xa, N_NODES, tc, F_IN / 8);
  cast_pad_kernel<<<(unsigned)((tc + 255) / 256), 256, 0, stream>>>(community_x, Xc, N_NODES, tc, F_IN / 8);

  // 4. CSR build for the three edge sets
  const int etot = E_WB + E_MB + E_INT;
  count_all_kernel<<<(etot + 255) / 256, 256, 0, stream>>>(e_wb + E_WB, e_mb + E_MB, e_int + E_INT,
                                                           cnt_wb, cnt_mb, cnt_int);
  scan3_kernel<<<3, 1024, 0, stream>>>(cnt_wb, cnt_mb, cnt_int, off_wb, off_mb, off_int);
  fill_all_kernel<<<(etot + 255) / 256, 256, 0, stream>>>(e_wb, e_mb, e_int, off_wb, off_mb, off_int,
                                                          cur_wb, cur_mb, cur_int,
                                                          srcl_wb, srcl_mb, srcl_int);

  // 5. big projections: AP = Xa @ [W1Wl1|W1Wl2], CR = Xc @ [W2Wr1|Wr3]
  gemm_bt_kernel<0><<<MT_ * 4, 256, 0, stream>>>(Xa, F12T, AP, F_IN, 512, N_NODES, nullptr, nullptr, 0);
  gemm_bt_kernel<0><<<MT_ * 4, 256, 0, stream>>>(Xc, GT, CR, F_IN, 512, N_NODES, nullptr, nullptr, 0);

  // 6. conv1: h1 = relu(mean_wb(ap1) + [deg>0]*gb1 + (bl1 + b2@Wr1) + cr1)
  agg_kernel<0><<<M_PAD, 64, 0, stream>>>(AP, 512, off_wb, srcl_wb, gb1, bv1, CR, 512, h1bf);

  // 7. conv2: HR2 = h1 @ Wr2 ; h2 = relu(mean_mb(ap2) + [deg>0]*gb2 + bl2 + HR2)
  gemm_bt_kernel<0><<<MT_ * 2, 256, 0, stream>>>(h1bf, Wr2T, HR2, HID, HID, N_NODES, nullptr, nullptr, 0);
  agg_kernel<1><<<M_PAD, 64, 0, stream>>>(AP + 256, 512, off_mb, srcl_mb, gb2, bl2, HR2, 256, h2bf);

  // 8. conv3: mean3 = mean_int(h2) ; h3 = relu(mean3 @ Wl3 + bl3 + cr3)
  agg_kernel<2><<<M_PAD, 64, 0, stream>>>(h2bf, 256, off_int, srcl_int, nullptr, nullptr, nullptr, 0, mean3bf);
  gemm_bt_kernel<1><<<MT_ * 2, 256, 0, stream>>>(mean3bf, Wl3T, h3bf, HID, HID, N_NODES, bl3, CR + 256, 512);

  // 9. out = h3 @ W3 + b3 (fp32)
  gemm_bt_kernel<2><<<MT_ * 1, 256, 0, stream>>>(h3bf, W3T, d_out, HID, OUTD, N_NODES, b3, nullptr, 0);

  (void)in_sizes; (void)n_in; (void)out_size; (void)ws_size;
}

// Round 2
// 935.345 us; speedup vs baseline: 1.2313x; 1.2313x over previous
//
#include <hip/hip_runtime.h>
#include <hip/hip_bf16.h>

#define N_NODES 50000
#define M_PAD   50048   /* 391 * 128 */
#define MT_     391
#define F_IN    768
#define PROJ    1024
#define HID     256
#define OUTD    128
#define E_WB    200000
#define E_MB    200000
#define E_INT   500000

typedef float f32x4 __attribute__((ext_vector_type(4)));
typedef __bf16 bf16x8 __attribute__((ext_vector_type(8)));

__device__ __forceinline__ float bf2f(unsigned short u) {
  union { unsigned int i; float f; } x; x.i = ((unsigned int)u) << 16; return x.f;
}
__device__ __forceinline__ unsigned short f2bf(float f) {
  union { float f; unsigned int i; } x; x.f = f;
  unsigned int r = x.i + 0x7fff + ((x.i >> 16) & 1);
  return (unsigned short)(r >> 16);
}

// async global->LDS, 16B per lane; lds dest must be wave-uniform base (+lane*16 implicit)
__device__ __forceinline__ void gl_lds16(const void* g, void* l) {
  __builtin_amdgcn_global_load_lds((const __attribute__((address_space(1))) void*)g,
                                   (__attribute__((address_space(3))) void*)l, 16, 0, 0);
}

// bv1 = bl1 + b2@Wr1, gb1 = b1@Wl1, gb2 = b1@Wl2  (all [256])
// grid: 24 blocks = out(3) x pchunk(8); outputs must be pre-zeroed.
__global__ void bias_prep_kernel(const float* __restrict__ b1, const float* __restrict__ b2,
                                 const float* __restrict__ bl1,
                                 const float* __restrict__ Wl1, const float* __restrict__ Wl2,
                                 const float* __restrict__ Wr1,
                                 float* __restrict__ gb1, float* __restrict__ gb2,
                                 float* __restrict__ bv1) {
  int j = threadIdx.x;           // 256
  int out = blockIdx.x >> 3;
  int pg = blockIdx.x & 7;
  const float* vb = (out == 2) ? b2 : b1;
  const float* W = (out == 0) ? Wl1 : (out == 1 ? Wl2 : Wr1);
  float s = 0.f;
  int p0 = pg * 128;
#pragma unroll 4
  for (int p = p0; p < p0 + 128; ++p) s += vb[p] * W[p * HID + j];
  if (out == 2 && pg == 0) s += bl1[j];
  float* dst = (out == 0) ? gb1 : (out == 1 ? gb2 : bv1);
  atomicAdd(&dst[j], s);
}

// transpose + cast fp32 [R][C] -> bf16 [C][R]
__global__ void tcast_kernel(const float* __restrict__ src, unsigned short* __restrict__ dst,
                             int R, int C) {
  __shared__ float tile[32][33];
  int x = blockIdx.x * 32 + threadIdx.x;
  int y0 = blockIdx.y * 32;
  for (int i = threadIdx.y; i < 32; i += blockDim.y)
    tile[i][threadIdx.x] = src[(long long)(y0 + i) * C + x];
  __syncthreads();
  int xo = blockIdx.y * 32 + threadIdx.x;
  int yo0 = blockIdx.x * 32;
  for (int i = threadIdx.y; i < 32; i += blockDim.y)
    dst[(long long)(yo0 + i) * R + xo] = f2bf(tile[threadIdx.x][i]);
}

// fp32 [rows_valid][cols] -> bf16 [rows_pad][cols], pad rows zeroed. one 16B chunk / thread
__global__ void cast_pad_kernel(const float* __restrict__ src, unsigned short* __restrict__ dst,
                                int rows_valid, long long total_chunks, int cpr) {
  long long i = (long long)blockIdx.x * 256 + threadIdx.x;
  if (i >= total_chunks) return;
  int row = (int)(i / cpr);
  int c8 = (int)(i % cpr);
  uint4 o;
  if (row < rows_valid) {
    const float4* s4 = (const float4*)src;
    long long base = (long long)row * (cpr * 2) + c8 * 2;
    float4 a = s4[base], b = s4[base + 1];
    o.x = (unsigned int)f2bf(a.x) | ((unsigned int)f2bf(a.y) << 16);
    o.y = (unsigned int)f2bf(a.z) | ((unsigned int)f2bf(a.w) << 16);
    o.z = (unsigned int)f2bf(b.x) | ((unsigned int)f2bf(b.y) << 16);
    o.w = (unsigned int)f2bf(b.z) | ((unsigned int)f2bf(b.w) << 16);
  } else {
    o.x = o.y = o.z = o.w = 0u;
  }
  ((uint4*)dst)[i] = o;
}

// ---------------- CSR build ----------------
__global__ void count_all_kernel(const int* __restrict__ dwb, const int* __restrict__ dmb,
                                 const int* __restrict__ dint,
                                 int* __restrict__ cwb, int* __restrict__ cmb,
                                 int* __restrict__ cint) {
  int i = blockIdx.x * blockDim.x + threadIdx.x;
  const int total = E_WB + E_MB + E_INT;
  if (i >= total) return;
  if (i < E_WB) atomicAdd(&cwb[dwb[i]], 1);
  else if (i < E_WB + E_MB) atomicAdd(&cmb[dmb[i - E_WB]], 1);
  else atomicAdd(&cint[dint[i - E_WB - E_MB]], 1);
}

__global__ void scan3_kernel(const int* __restrict__ c0, const int* __restrict__ c1,
                             const int* __restrict__ c2,
                             int* __restrict__ o0, int* __restrict__ o1, int* __restrict__ o2) {
  const int* cnt = blockIdx.x == 0 ? c0 : (blockIdx.x == 1 ? c1 : c2);
  int* off = blockIdx.x == 0 ? o0 : (blockIdx.x == 1 ? o1 : o2);
  const int n = N_NODES;
  __shared__ int part[1024];
  int t = threadIdx.x;
  const int chunk = (n + 1023) / 1024;
  int lo = t * chunk, hi = lo + chunk; if (hi > n) hi = n; if (lo > n) lo = n;
  int s = 0;
  for (int i = lo; i < hi; ++i) s += cnt[i];
  part[t] = s; __syncthreads();
  for (int d = 1; d < 1024; d <<= 1) {
    int v = part[t];
    if (t >= d) v += part[t - d];
    __syncthreads();
    part[t] = v;
    __syncthreads();
  }
  int run = (t == 0) ? 0 : part[t - 1];
  for (int i = lo; i < hi; ++i) { off[i] = run; run += cnt[i]; }
  if (t == 1023) off[n] = part[1023];
}

__global__ void fill_all_kernel(const int* __restrict__ ewb, const int* __restrict__ emb,
                                const int* __restrict__ eint,
                                const int* __restrict__ owb, const int* __restrict__ omb,
                                const int* __restrict__ oint,
                                int* __restrict__ curwb, int* __restrict__ curmb,
                                int* __restrict__ curint,
                                int* __restrict__ swb, int* __restrict__ smb,
                                int* __restrict__ sint) {
  int i = blockIdx.x * blockDim.x + threadIdx.x;
  const int total = E_WB + E_MB + E_INT;
  if (i >= total) return;
  if (i < E_WB) {
    int s = ewb[i], d = ewb[E_WB + i];
    int p = atomicAdd(&curwb[d], 1);
    swb[owb[d] + p] = s;
  } else if (i < E_WB + E_MB) {
    int e = i - E_WB;
    int s = emb[e], d = emb[E_MB + e];
    int p = atomicAdd(&curmb[d], 1);
    smb[omb[d] + p] = s;
  } else {
    int e = i - E_WB - E_MB;
    int s = eint[e], d = eint[E_INT + e];
    int p = atomicAdd(&curint[d], 1);
    sint[oint[d] + p] = s;
  }
}

// ---------------- GEMM: C[M][N] = A[M][K](bf16) * BT[N][K](bf16)^T ----------------
// m97 structure: async global_load_lds (16B/lane) staging, 2-barrier K-loop.
// EPI 0: store bf16.  EPI 1: relu(acc + bias[c] + bf2f(addm)) -> bf16.  EPI 2: acc + bias[c] -> fp32
template <int EPI>
__global__ void __launch_bounds__(256, 2)
gemm_bt_kernel(const unsigned short* __restrict__ A, const unsigned short* __restrict__ BT,
               void* __restrict__ Cv, int K, int N, int Mvalid,
               const float* __restrict__ bias, const unsigned short* __restrict__ addm,
               int addm_stride) {
  __shared__ __align__(16) unsigned short lA[128 * 32];
  __shared__ __align__(16) unsigned short lB[128 * 32];
  const int tid = threadIdx.x;
  const int lane = tid & 63;
  const int wave = tid >> 6;
  const int NT = N >> 7;
  const int mt = blockIdx.x / NT;
  const int nt = blockIdx.x % NT;
  const int m0 = mt * 128, n0 = nt * 128;
  const int wm = (wave & 1) * 64, wn = (wave >> 1) * 64;

  f32x4 acc[4][4];
#pragma unroll
  for (int i = 0; i < 4; ++i)
#pragma unroll
    for (int j = 0; j < 4; ++j)
#pragma unroll
      for (int r = 0; r < 4; ++r) acc[i][j][r] = 0.f;

  const int r0 = tid >> 2;              // LDS row this lane stages (tid*16B == (r0,c0))
  const int c0 = (tid & 3) * 8;
  const uint4* A4 = (const uint4*)A;
  const uint4* B4 = (const uint4*)BT;
  const int K8 = K >> 3;
  const int mrow = lane & 15, kq = lane >> 4;
  unsigned short* lAw = &lA[wave * 512];    // wave-uniform LDS bases (lane*16B implicit)
  unsigned short* lBw = &lB[wave * 512];

  for (int kt = 0; kt < K; kt += 32) {
    const int kc = (kt + c0) >> 3;
    __syncthreads();   // previous iteration's LDS readers done
    gl_lds16(&A4[(long long)(m0 + r0) * K8 + kc], lAw);
    gl_lds16(&A4[(long long)(m0 + 64 + r0) * K8 + kc], lAw + 2048);
    gl_lds16(&B4[(long long)(n0 + r0) * K8 + kc], lBw);
    gl_lds16(&B4[(long long)(n0 + 64 + r0) * K8 + kc], lBw + 2048);
    __syncthreads();   // drains vmcnt -> staged data visible
    bf16x8 af[4], bfr[4];
#pragma unroll
    for (int i = 0; i < 4; ++i) af[i] = *(const bf16x8*)&lA[(wm + i * 16 + mrow) * 32 + kq * 8];
#pragma unroll
    for (int j = 0; j < 4; ++j) bfr[j] = *(const bf16x8*)&lB[(wn + j * 16 + mrow) * 32 + kq * 8];
#pragma unroll
    for (int i = 0; i < 4; ++i)
#pragma unroll
      for (int j = 0; j < 4; ++j)
        acc[i][j] = __builtin_amdgcn_mfma_f32_16x16x32_bf16(af[i], bfr[j], acc[i][j], 0, 0, 0);
  }

  const int col_l = lane & 15, rq = lane >> 4;
#pragma unroll
  for (int i = 0; i < 4; ++i) {
#pragma unroll
    for (int j = 0; j < 4; ++j) {
#pragma unroll
      for (int r = 0; r < 4; ++r) {
        int R = m0 + wm + i * 16 + rq * 4 + r;
        int Cc = n0 + wn + j * 16 + col_l;
        if (R < Mvalid) {
          float v = acc[i][j][r];
          if constexpr (EPI == 0) {
            ((unsigned short*)Cv)[(long long)R * N + Cc] = f2bf(v);
          } else if constexpr (EPI == 1) {
            v += bias[Cc] + bf2f(addm[(long long)R * addm_stride + Cc]);
            v = v > 0.f ? v : 0.f;
            ((unsigned short*)Cv)[(long long)R * N + Cc] = f2bf(v);
          } else {
            ((float*)Cv)[(long long)R * N + Cc] = v + bias[Cc];
          }
        }
      }
    }
  }
}

// ---------------- aggregation: one wave per dst row, 4 cols per lane ----------------
template <int MODE>
__global__ void agg_kernel(const unsigned short* __restrict__ S, int s_stride,
                           const int* __restrict__ off, const int* __restrict__ srcl,
                           const float* __restrict__ gb, const float* __restrict__ bvec,
                           const unsigned short* __restrict__ addm, int a_stride,
                           unsigned short* __restrict__ out) {
  int d = blockIdx.x;
  int c = threadIdx.x * 4;
  if (d >= N_NODES) {
    ushort4 z; z.x = z.y = z.z = z.w = 0;
    *(ushort4*)&out[(long long)d * HID + c] = z;
    return;
  }
  int lo = off[d], hi = off[d + 1];
  float s0 = 0.f, s1 = 0.f, s2 = 0.f, s3 = 0.f;
  for (int i = lo; i < hi; ++i) {
    int sidx = srcl[i];
    uint2 v = *(const uint2*)&S[(long long)sidx * s_stride + c];
    s0 += bf2f((unsigned short)(v.x & 0xffff));
    s1 += bf2f((unsigned short)(v.x >> 16));
    s2 += bf2f((unsigned short)(v.y & 0xffff));
    s3 += bf2f((unsigned short)(v.y >> 16));
  }
  int deg = hi - lo;
  float inv = deg > 0 ? 1.f / (float)deg : 0.f;
  float v0 = s0 * inv, v1 = s1 * inv, v2 = s2 * inv, v3 = s3 * inv;
  if constexpr (MODE != 2) {
    float g = deg > 0 ? 1.f : 0.f;
    uint2 am = *(const uint2*)&addm[(long long)d * a_stride + c];
    v0 += g * gb[c] + bvec[c] + bf2f((unsigned short)(am.x & 0xffff));
    v1 += g * gb[c + 1] + bvec[c + 1] + bf2f((unsigned short)(am.x >> 16));
    v2 += g * gb[c + 2] + bvec[c + 2] + bf2f((unsigned short)(am.y & 0xffff));
    v3 += g * gb[c + 3] + bvec[c + 3] + bf2f((unsigned short)(am.y >> 16));
    v0 = fmaxf(v0, 0.f); v1 = fmaxf(v1, 0.f); v2 = fmaxf(v2, 0.f); v3 = fmaxf(v3, 0.f);
  }
  ushort4 o;
  o.x = f2bf(v0); o.y = f2bf(v1); o.z = f2bf(v2); o.w = f2bf(v3);
  *(ushort4*)&out[(long long)d * HID + c] = o;
}

extern "C" void kernel_launch(void* const* d_in, const int* in_sizes, int n_in,
                              void* d_out, int out_size, void* d_ws, size_t ws_size,
                              hipStream_t stream) {
  const float* article_x = (const float*)d_in[0];
  const float* community_x = (const float*)d_in[1];
  const int* e_wb = (const int*)d_in[2];
  const int* e_mb = (const int*)d_in[3];
  const int* e_int = (const int*)d_in[4];
  const float* W1 = (const float*)d_in[5];
  const float* b1 = (const float*)d_in[6];
  const float* W2 = (const float*)d_in[7];
  const float* b2 = (const float*)d_in[8];
  const float* Wl1 = (const float*)d_in[9];
  const float* bl1 = (const float*)d_in[10];
  const float* Wr1 = (const float*)d_in[11];
  const float* Wl2 = (const float*)d_in[12];
  const float* bl2 = (const float*)d_in[13];
  const float* Wr2 = (const float*)d_in[14];
  const float* Wl3 = (const float*)d_in[15];
  const float* bl3 = (const float*)d_in[16];
  const float* Wr3 = (const float*)d_in[17];
  const float* W3 = (const float*)d_in[18];
  const float* b3 = (const float*)d_in[19];

  char* base = (char*)d_ws;
  size_t off = 0;
  auto alloc = [&](size_t bytes) -> void* {
    void* r = base + off;
    off += (bytes + 255) & ~(size_t)255;
    return r;
  };

  unsigned short* Xa = (unsigned short*)alloc((size_t)M_PAD * F_IN * 2);
  unsigned short* Xc = (unsigned short*)alloc((size_t)M_PAD * F_IN * 2);
  unsigned short* AP = (unsigned short*)alloc((size_t)M_PAD * 512 * 2);
  unsigned short* CR = (unsigned short*)alloc((size_t)M_PAD * 512 * 2);
  unsigned short* h1bf = (unsigned short*)alloc((size_t)M_PAD * HID * 2);
  unsigned short* HR2 = (unsigned short*)alloc((size_t)M_PAD * HID * 2);
  unsigned short* h2bf = (unsigned short*)alloc((size_t)M_PAD * HID * 2);
  unsigned short* mean3bf = (unsigned short*)alloc((size_t)M_PAD * HID * 2);
  unsigned short* h3bf = (unsigned short*)alloc((size_t)M_PAD * HID * 2);
  unsigned short* W1bf = (unsigned short*)alloc((size_t)F_IN * PROJ * 2);
  unsigned short* W2bf = (unsigned short*)alloc((size_t)F_IN * PROJ * 2);
  unsigned short* WlT = (unsigned short*)alloc((size_t)512 * PROJ * 2);   // [Wl1^T; Wl2^T]
  unsigned short* Wr1T = (unsigned short*)alloc((size_t)HID * PROJ * 2);
  unsigned short* F12T = (unsigned short*)alloc((size_t)512 * F_IN * 2);  // fused [512][768]
  unsigned short* GT = (unsigned short*)alloc((size_t)512 * F_IN * 2);    // fused [512][768]
  unsigned short* Wr2T = (unsigned short*)alloc((size_t)HID * HID * 2);
  unsigned short* Wl3T = (unsigned short*)alloc((size_t)HID * HID * 2);
  unsigned short* W3T = (unsigned short*)alloc((size_t)OUTD * HID * 2);
  float* gb1 = (float*)alloc(HID * 4);   // these three stay contiguous (1KB each, 256-aligned)
  float* gb2 = (float*)alloc(HID * 4);
  float* bv1 = (float*)alloc(HID * 4);
  int* ints_base = (int*)alloc((size_t)6 * N_NODES * 4);
  int* cnt_wb = ints_base;
  int* cur_wb = ints_base + N_NODES;
  int* cnt_mb = ints_base + 2 * N_NODES;
  int* cur_mb = ints_base + 3 * N_NODES;
  int* cnt_int = ints_base + 4 * N_NODES;
  int* cur_int = ints_base + 5 * N_NODES;
  int* off_wb = (int*)alloc((size_t)(N_NODES + 1) * 4);
  int* off_mb = (int*)alloc((size_t)(N_NODES + 1) * 4);
  int* off_int = (int*)alloc((size_t)(N_NODES + 1) * 4);
  int* srcl_wb = (int*)alloc((size_t)E_WB * 4);
  int* srcl_mb = (int*)alloc((size_t)E_MB * 4);
  int* srcl_int = (int*)alloc((size_t)E_INT * 4);

  // 1. zero histogram/cursor region + bias accumulators
  hipMemsetAsync(ints_base, 0, (size_t)6 * N_NODES * 4, stream);
  hipMemsetAsync(gb1, 0, 3 * 1024, stream);

  // 2. weight casts/transposes (all small)
  cast_pad_kernel<<<(F_IN * PROJ / 8 + 255) / 256, 256, 0, stream>>>(W1, W1bf, F_IN, F_IN * (PROJ / 8), PROJ / 8);
  cast_pad_kernel<<<(F_IN * PROJ / 8 + 255) / 256, 256, 0, stream>>>(W2, W2bf, F_IN, F_IN * (PROJ / 8), PROJ / 8);
  tcast_kernel<<<dim3(HID / 32, PROJ / 32), dim3(32, 8), 0, stream>>>(Wl1, WlT, PROJ, HID);
  tcast_kernel<<<dim3(HID / 32, PROJ / 32), dim3(32, 8), 0, stream>>>(Wl2, WlT + 256 * PROJ, PROJ, HID);
  tcast_kernel<<<dim3(HID / 32, PROJ / 32), dim3(32, 8), 0, stream>>>(Wr1, Wr1T, PROJ, HID);
  tcast_kernel<<<dim3(HID / 32, F_IN / 32), dim3(32, 8), 0, stream>>>(Wr3, GT + 256 * F_IN, F_IN, HID);
  tcast_kernel<<<dim3(8, 8), dim3(32, 8), 0, stream>>>(Wr2, Wr2T, HID, HID);
  tcast_kernel<<<dim3(8, 8), dim3(32, 8), 0, stream>>>(Wl3, Wl3T, HID, HID);
  tcast_kernel<<<dim3(4, 8), dim3(32, 8), 0, stream>>>(W3, W3T, HID, OUTD);
  bias_prep_kernel<<<24, 256, 0, stream>>>(b1, b2, bl1, Wl1, Wl2, Wr1, gb1, gb2, bv1);

  // 3. fused weights via MFMA (transposed output layout, directly consumable as BT):
  //    F12T[512][768] = WlT[512][1024] @ W1bf[768][1024]^T ;  GT[0:256][768] = Wr1T @ W2bf^T
  gemm_bt_kernel<0><<<4 * 6, 256, 0, stream>>>(WlT, W1bf, F12T, PROJ, F_IN, 512, nullptr, nullptr, 0);
  gemm_bt_kernel<0><<<2 * 6, 256, 0, stream>>>(Wr1T, W2bf, GT, PROJ, F_IN, 256, nullptr, nullptr, 0);

  // 4. cast node features to bf16 (zero-padded to M_PAD rows)
  long long tc = (long long)M_PAD * (F_IN / 8);
  cast_pad_kernel<<<(unsigned)((tc + 255) / 256), 256, 0, stream>>>(article_x, Xa, N_NODES, tc, F_IN / 8);
  cast_pad_kernel<<<(unsigned)((tc + 255) / 256), 256, 0, stream>>>(community_x, Xc, N_NODES, tc, F_IN / 8);

  // 5. CSR build for the three edge sets
  const int etot = E_WB + E_MB + E_INT;
  count_all_kernel<<<(etot + 255) / 256, 256, 0, stream>>>(e_wb + E_WB, e_mb + E_MB, e_int + E_INT,
                                                           cnt_wb, cnt_mb, cnt_int);
  scan3_kernel<<<3, 1024, 0, stream>>>(cnt_wb, cnt_mb, cnt_int, off_wb, off_mb, off_int);
  fill_all_kernel<<<(etot + 255) / 256, 256, 0, stream>>>(e_wb, e_mb, e_int, off_wb, off_mb, off_int,
                                                          cur_wb, cur_mb, cur_int,
                                                          srcl_wb, srcl_mb, srcl_int);

  // 6. big projections: AP = Xa @ F12T^T, CR = Xc @ GT^T   (both [M_PAD][512])
  gemm_bt_kernel<0><<<MT_ * 4, 256, 0, stream>>>(Xa, F12T, AP, F_IN, 512, N_NODES, nullptr, nullptr, 0);
  gemm_bt_kernel<0><<<MT_ * 4, 256, 0, stream>>>(Xc, GT, CR, F_IN, 512, N_NODES, nullptr, nullptr, 0);

  // 7. conv1: h1 = relu(mean_wb(ap1) + [deg>0]*gb1 + (bl1 + b2@Wr1) + cr1)
  agg_kernel<0><<<M_PAD, 64, 0, stream>>>(AP, 512, off_wb, srcl_wb, gb1, bv1, CR, 512, h1bf);

  // 8. conv2: HR2 = h1 @ Wr2 ; h2 = relu(mean_mb(ap2) + [deg>0]*gb2 + bl2 + HR2)
  gemm_bt_kernel<0><<<MT_ * 2, 256, 0, stream>>>(h1bf, Wr2T, HR2, HID, HID, N_NODES, nullptr, nullptr, 0);
  agg_kernel<1><<<M_PAD, 64, 0, stream>>>(AP + 256, 512, off_mb, srcl_mb, gb2, bl2, HR2, 256, h2bf);

  // 9. conv3: mean3 = mean_int(h2) ; h3 = relu(mean3 @ Wl3 + bl3 + cr3)
  agg_kernel<2><<<M_PAD, 64, 0, stream>>>(h2bf, 256, off_int, srcl_int, nullptr, nullptr, nullptr, 0, mean3bf);
  gemm_bt_kernel<1><<<MT_ * 2, 256, 0, stream>>>(mean3bf, Wl3T, h3bf, HID, HID, N_NODES, bl3, CR + 256, 512);

  // 10. out = h3 @ W3 + b3 (fp32)
  gemm_bt_kernel<2><<<MT_ * 1, 256, 0, stream>>>(h3bf, W3T, d_out, HID, OUTD, N_NODES, b3, nullptr, 0);

  (void)in_sizes; (void)n_in; (void)out_size; (void)ws_size;
}

// Round 3
// 908.518 us; speedup vs baseline: 1.2677x; 1.0295x over previous
//
#include <hip/hip_runtime.h>
#include <hip/hip_bf16.h>

#define N_NODES 50000
#define M_PAD   50048   /* 391 * 128 */
#define MT_     391
#define F_IN    768
#define PROJ    1024
#define HID     256
#define OUTD    128
#define E_WB    200000
#define E_MB    200000
#define E_INT   500000
#define BIGM    (1 << 30)

typedef float f32x4 __attribute__((ext_vector_type(4)));
typedef __bf16 bf16x8 __attribute__((ext_vector_type(8)));

__device__ __forceinline__ float bf2f(unsigned short u) {
  union { unsigned int i; float f; } x; x.i = ((unsigned int)u) << 16; return x.f;
}
__device__ __forceinline__ unsigned short f2bf(float f) {
  union { float f; unsigned int i; } x; x.f = f;
  unsigned int r = x.i + 0x7fff + ((x.i >> 16) & 1);
  return (unsigned short)(r >> 16);
}

// async global->LDS, 16B per lane; lds dest is wave-uniform base (+lane*16 implicit)
__device__ __forceinline__ void gl_lds16(const void* g, void* l) {
  __builtin_amdgcn_global_load_lds((const __attribute__((address_space(1))) void*)g,
                                   (__attribute__((address_space(3))) void*)l, 16, 0, 0);
}

// ---------------- merged weight-prep kernel (sectioned) ----------------
// S0 castW1(384) S1 castW2(384) S2 Wl1T(256) S3 Wl2T(256) S4 Wr1T(256)
// S5 Wr3T(192) S6 Wr2T(64) S7 Wl3T(64) S8 W3T(32) S9 bias_prep(24)
__device__ __forceinline__ void dev_cast8(const float* __restrict__ src,
                                          unsigned short* __restrict__ dst, int blk) {
  int i = blk * 256 + threadIdx.x;     // one 8-elem chunk
  const float4* s4 = (const float4*)src;
  float4 a = s4[(long long)i * 2], b = s4[(long long)i * 2 + 1];
  uint4 o;
  o.x = (unsigned int)f2bf(a.x) | ((unsigned int)f2bf(a.y) << 16);
  o.y = (unsigned int)f2bf(a.z) | ((unsigned int)f2bf(a.w) << 16);
  o.z = (unsigned int)f2bf(b.x) | ((unsigned int)f2bf(b.y) << 16);
  o.w = (unsigned int)f2bf(b.z) | ((unsigned int)f2bf(b.w) << 16);
  ((uint4*)dst)[i] = o;
}

__device__ __forceinline__ void dev_tcast(const float* __restrict__ src,
                                          unsigned short* __restrict__ dst,
                                          int R, int C, int blk, float (*tile)[33]) {
  int bx = blk % (C / 32), by = blk / (C / 32);
  int tx = threadIdx.x & 31, ty = threadIdx.x >> 5;   // 32 x 8
  int x = bx * 32 + tx, y0 = by * 32;
  for (int i = ty; i < 32; i += 8) tile[i][tx] = src[(long long)(y0 + i) * C + x];
  __syncthreads();
  int xo = by * 32 + tx, yo0 = bx * 32;
  for (int i = ty; i < 32; i += 8) dst[(long long)(yo0 + i) * R + xo] = f2bf(tile[tx][i]);
}

__global__ void prep_all_kernel(const float* __restrict__ W1, const float* __restrict__ W2,
                                const float* __restrict__ Wl1, const float* __restrict__ Wl2,
                                const float* __restrict__ Wr1, const float* __restrict__ Wr2,
                                const float* __restrict__ Wl3, const float* __restrict__ Wr3,
                                const float* __restrict__ W3,
                                const float* __restrict__ b1, const float* __restrict__ b2,
                                const float* __restrict__ bl1,
                                unsigned short* __restrict__ W1bf, unsigned short* __restrict__ W2bf,
                                unsigned short* __restrict__ WlT, unsigned short* __restrict__ Wr1T,
                                unsigned short* __restrict__ GT_wr3, unsigned short* __restrict__ Wr2T,
                                unsigned short* __restrict__ Wl3T, unsigned short* __restrict__ W3T,
                                float* __restrict__ gb1, float* __restrict__ gb2,
                                float* __restrict__ bv1) {
  __shared__ float tile[32][33];
  int b = blockIdx.x;
  if (b < 384) { dev_cast8(W1, W1bf, b); return; }
  b -= 384;
  if (b < 384) { dev_cast8(W2, W2bf, b); return; }
  b -= 384;
  if (b < 256) { dev_tcast(Wl1, WlT, PROJ, HID, b, tile); return; }
  b -= 256;
  if (b < 256) { dev_tcast(Wl2, WlT + 256 * PROJ, PROJ, HID, b, tile); return; }
  b -= 256;
  if (b < 256) { dev_tcast(Wr1, Wr1T, PROJ, HID, b, tile); return; }
  b -= 256;
  if (b < 192) { dev_tcast(Wr3, GT_wr3, F_IN, HID, b, tile); return; }
  b -= 192;
  if (b < 64) { dev_tcast(Wr2, Wr2T, HID, HID, b, tile); return; }
  b -= 64;
  if (b < 64) { dev_tcast(Wl3, Wl3T, HID, HID, b, tile); return; }
  b -= 64;
  if (b < 32) { dev_tcast(W3, W3T, HID, OUTD, b, tile); return; }
  b -= 32;
  // bias_prep: 24 blocks = out(3) x pchunk(8); outputs pre-zeroed
  int j = threadIdx.x;
  int out = b >> 3, pg = b & 7;
  const float* vb = (out == 2) ? b2 : b1;
  const float* W = (out == 0) ? Wl1 : (out == 1 ? Wl2 : Wr1);
  float s = 0.f;
  int p0 = pg * 128;
#pragma unroll 4
  for (int p = p0; p < p0 + 128; ++p) s += vb[p] * W[p * HID + j];
  if (out == 2 && pg == 0) s += bl1[j];
  float* dst = (out == 0) ? gb1 : (out == 1 ? gb2 : bv1);
  atomicAdd(&dst[j], s);
}

// stacked node-feature cast: rows [0,M_PAD) from article, [M_PAD,2*M_PAD) from community
__global__ void cast_nodes_kernel(const float* __restrict__ ax, const float* __restrict__ cx,
                                  unsigned short* __restrict__ dst) {
  int i = blockIdx.x * 256 + threadIdx.x;            // 8-elem chunk, 96 per row
  int row = i / 96, c8 = i % 96;
  const float* src = ax;
  int vrow = row;
  if (row >= M_PAD) { src = cx; vrow = row - M_PAD; }
  uint4 o;
  if (vrow < N_NODES) {
    const float4* s4 = (const float4*)src;
    long long base = (long long)vrow * 192 + c8 * 2;
    float4 a = s4[base], bq = s4[base + 1];
    o.x = (unsigned int)f2bf(a.x) | ((unsigned int)f2bf(a.y) << 16);
    o.y = (unsigned int)f2bf(a.z) | ((unsigned int)f2bf(a.w) << 16);
    o.z = (unsigned int)f2bf(bq.x) | ((unsigned int)f2bf(bq.y) << 16);
    o.w = (unsigned int)f2bf(bq.z) | ((unsigned int)f2bf(bq.w) << 16);
  } else {
    o.x = o.y = o.z = o.w = 0u;
  }
  ((uint4*)dst)[i] = o;
}

// ---------------- CSR build ----------------
__global__ void count_all_kernel(const int* __restrict__ dwb, const int* __restrict__ dmb,
                                 const int* __restrict__ dint,
                                 int* __restrict__ cwb, int* __restrict__ cmb,
                                 int* __restrict__ cint) {
  int i = blockIdx.x * blockDim.x + threadIdx.x;
  const int total = E_WB + E_MB + E_INT;
  if (i >= total) return;
  if (i < E_WB) atomicAdd(&cwb[dwb[i]], 1);
  else if (i < E_WB + E_MB) atomicAdd(&cmb[dmb[i - E_WB]], 1);
  else atomicAdd(&cint[dint[i - E_WB - E_MB]], 1);
}

__global__ void scan3_kernel(const int* __restrict__ c0, const int* __restrict__ c1,
                             const int* __restrict__ c2,
                             int* __restrict__ o0, int* __restrict__ o1, int* __restrict__ o2) {
  const int* cnt = blockIdx.x == 0 ? c0 : (blockIdx.x == 1 ? c1 : c2);
  int* off = blockIdx.x == 0 ? o0 : (blockIdx.x == 1 ? o1 : o2);
  const int n = N_NODES;
  __shared__ int part[1024];
  int t = threadIdx.x;
  const int chunk = (n + 1023) / 1024;
  int lo = t * chunk, hi = lo + chunk; if (hi > n) hi = n; if (lo > n) lo = n;
  int s = 0;
  for (int i = lo; i < hi; ++i) s += cnt[i];
  part[t] = s; __syncthreads();
  for (int d = 1; d < 1024; d <<= 1) {
    int v = part[t];
    if (t >= d) v += part[t - d];
    __syncthreads();
    part[t] = v;
    __syncthreads();
  }
  int run = (t == 0) ? 0 : part[t - 1];
  for (int i = lo; i < hi; ++i) { off[i] = run; run += cnt[i]; }
  if (t == 1023) off[n] = part[1023];
}

__global__ void fill_all_kernel(const int* __restrict__ ewb, const int* __restrict__ emb,
                                const int* __restrict__ eint,
                                const int* __restrict__ owb, const int* __restrict__ omb,
                                const int* __restrict__ oint,
                                int* __restrict__ curwb, int* __restrict__ curmb,
                                int* __restrict__ curint,
                                int* __restrict__ swb, int* __restrict__ smb,
                                int* __restrict__ sint) {
  int i = blockIdx.x * blockDim.x + threadIdx.x;
  const int total = E_WB + E_MB + E_INT;
  if (i >= total) return;
  if (i < E_WB) {
    int s = ewb[i], d = ewb[E_WB + i];
    int p = atomicAdd(&curwb[d], 1);
    swb[owb[d] + p] = s;
  } else if (i < E_WB + E_MB) {
    int e = i - E_WB;
    int s = emb[e], d = emb[E_MB + e];
    int p = atomicAdd(&curmb[d], 1);
    smb[omb[d] + p] = s;
  } else {
    int e = i - E_WB - E_MB;
    int s = eint[e], d = eint[E_INT + e];
    int p = atomicAdd(&curint[d], 1);
    sint[oint[d] + p] = s;
  }
}

// ---------------- GEMM: C[M][N] = A[M][K](bf16) * BT[N][K](bf16)^T ----------------
// BK=64 K-loop (2 sub-tiles per barrier pair), async global_load_lds staging.
// BT = (mt < mt_split) ? BT0 : BT1 — lets two stacked GEMMs share one launch.
// Store-row validity: vr = (R >= Mhalf ? R - Mhalf : R) < Mvalid.
// EPI 0: bf16.  EPI 1: relu(acc + bias[c] + bf2f(addm)) bf16.  EPI 2: acc + bias[c] fp32.
template <int EPI>
__global__ void __launch_bounds__(256, 2)
gemm_bt_kernel(const unsigned short* __restrict__ A, const unsigned short* __restrict__ BT0,
               const unsigned short* __restrict__ BT1, int mt_split,
               void* __restrict__ Cv, int K, int N, int Mhalf, int Mvalid,
               const float* __restrict__ bias, const unsigned short* __restrict__ addm,
               int addm_stride) {
  __shared__ __align__(16) unsigned short lA[2 * 4096];
  __shared__ __align__(16) unsigned short lB[2 * 4096];
  const int tid = threadIdx.x;
  const int lane = tid & 63;
  const int wave = tid >> 6;
  const int NT = N >> 7;
  const int mt = blockIdx.x / NT;
  const int nt = blockIdx.x % NT;
  const int m0 = mt * 128, n0 = nt * 128;
  const int wm = (wave & 1) * 64, wn = (wave >> 1) * 64;
  const unsigned short* BT = (mt < mt_split) ? BT0 : BT1;

  f32x4 acc[4][4];
#pragma unroll
  for (int i = 0; i < 4; ++i)
#pragma unroll
    for (int j = 0; j < 4; ++j)
#pragma unroll
      for (int r = 0; r < 4; ++r) acc[i][j][r] = 0.f;

  const int r0 = tid >> 2;              // LDS row this lane stages (tid*16B)
  const int c0 = (tid & 3) * 8;
  const uint4* A4 = (const uint4*)A;
  const uint4* B4 = (const uint4*)BT;
  const int K8 = K >> 3;
  const int mrow = lane & 15, kq = lane >> 4;

  for (int kt = 0; kt < K; kt += 64) {
    __syncthreads();   // previous iteration's LDS readers done
#pragma unroll
    for (int s = 0; s < 2; ++s) {
      const int kc = (kt + s * 32 + c0) >> 3;
      unsigned short* lAw = &lA[s * 4096 + wave * 512];
      unsigned short* lBw = &lB[s * 4096 + wave * 512];
      gl_lds16(&A4[(long long)(m0 + r0) * K8 + kc], lAw);
      gl_lds16(&A4[(long long)(m0 + 64 + r0) * K8 + kc], lAw + 2048);
      gl_lds16(&B4[(long long)(n0 + r0) * K8 + kc], lBw);
      gl_lds16(&B4[(long long)(n0 + 64 + r0) * K8 + kc], lBw + 2048);
    }
    __syncthreads();   // drains vmcnt -> staged data visible
#pragma unroll
    for (int s = 0; s < 2; ++s) {
      bf16x8 af[4], bfr[4];
#pragma unroll
      for (int i = 0; i < 4; ++i)
        af[i] = *(const bf16x8*)&lA[s * 4096 + (wm + i * 16 + mrow) * 32 + kq * 8];
#pragma unroll
      for (int j = 0; j < 4; ++j)
        bfr[j] = *(const bf16x8*)&lB[s * 4096 + (wn + j * 16 + mrow) * 32 + kq * 8];
#pragma unroll
      for (int i = 0; i < 4; ++i)
#pragma unroll
        for (int j = 0; j < 4; ++j)
          acc[i][j] = __builtin_amdgcn_mfma_f32_16x16x32_bf16(af[i], bfr[j], acc[i][j], 0, 0, 0);
    }
  }

  const int col_l = lane & 15, rq = lane >> 4;
#pragma unroll
  for (int i = 0; i < 4; ++i) {
#pragma unroll
    for (int j = 0; j < 4; ++j) {
#pragma unroll
      for (int r = 0; r < 4; ++r) {
        int R = m0 + wm + i * 16 + rq * 4 + r;
        int Cc = n0 + wn + j * 16 + col_l;
        int vr = (R >= Mhalf) ? R - Mhalf : R;
        if (vr < Mvalid) {
          float v = acc[i][j][r];
          if constexpr (EPI == 0) {
            ((unsigned short*)Cv)[(long long)R * N + Cc] = f2bf(v);
          } else if constexpr (EPI == 1) {
            v += bias[Cc] + bf2f(addm[(long long)R * addm_stride + Cc]);
            v = v > 0.f ? v : 0.f;
            ((unsigned short*)Cv)[(long long)R * N + Cc] = f2bf(v);
          } else {
            ((float*)Cv)[(long long)R * N + Cc] = v + bias[Cc];
          }
        }
      }
    }
  }
}

// ---------------- aggregation: 4 waves/block, one wave per dst row ----------------
template <int MODE>
__global__ void agg_kernel(const unsigned short* __restrict__ S, int s_stride,
                           const int* __restrict__ off, const int* __restrict__ srcl,
                           const float* __restrict__ gb, const float* __restrict__ bvec,
                           const unsigned short* __restrict__ addm, int a_stride,
                           unsigned short* __restrict__ out) {
  int d = blockIdx.x * 4 + (threadIdx.x >> 6);
  int c = (threadIdx.x & 63) * 4;
  if (d >= N_NODES) {
    ushort4 z; z.x = z.y = z.z = z.w = 0;
    *(ushort4*)&out[(long long)d * HID + c] = z;
    return;
  }
  int lo = off[d], hi = off[d + 1];
  float s0 = 0.f, s1 = 0.f, s2 = 0.f, s3 = 0.f;
  for (int i = lo; i < hi; ++i) {
    int sidx = srcl[i];
    uint2 v = *(const uint2*)&S[(long long)sidx * s_stride + c];
    s0 += bf2f((unsigned short)(v.x & 0xffff));
    s1 += bf2f((unsigned short)(v.x >> 16));
    s2 += bf2f((unsigned short)(v.y & 0xffff));
    s3 += bf2f((unsigned short)(v.y >> 16));
  }
  int deg = hi - lo;
  float inv = deg > 0 ? 1.f / (float)deg : 0.f;
  float v0 = s0 * inv, v1 = s1 * inv, v2 = s2 * inv, v3 = s3 * inv;
  if constexpr (MODE != 2) {
    float g = deg > 0 ? 1.f : 0.f;
    uint2 am = *(const uint2*)&addm[(long long)d * a_stride + c];
    v0 += g * gb[c] + bvec[c] + bf2f((unsigned short)(am.x & 0xffff));
    v1 += g * gb[c + 1] + bvec[c + 1] + bf2f((unsigned short)(am.x >> 16));
    v2 += g * gb[c + 2] + bvec[c + 2] + bf2f((unsigned short)(am.y & 0xffff));
    v3 += g * gb[c + 3] + bvec[c + 3] + bf2f((unsigned short)(am.y >> 16));
    v0 = fmaxf(v0, 0.f); v1 = fmaxf(v1, 0.f); v2 = fmaxf(v2, 0.f); v3 = fmaxf(v3, 0.f);
  }
  ushort4 o;
  o.x = f2bf(v0); o.y = f2bf(v1); o.z = f2bf(v2); o.w = f2bf(v3);
  *(ushort4*)&out[(long long)d * HID + c] = o;
}

extern "C" void kernel_launch(void* const* d_in, const int* in_sizes, int n_in,
                              void* d_out, int out_size, void* d_ws, size_t ws_size,
                              hipStream_t stream) {
  const float* article_x = (const float*)d_in[0];
  const float* community_x = (const float*)d_in[1];
  const int* e_wb = (const int*)d_in[2];
  const int* e_mb = (const int*)d_in[3];
  const int* e_int = (const int*)d_in[4];
  const float* W1 = (const float*)d_in[5];
  const float* b1 = (const float*)d_in[6];
  const float* W2 = (const float*)d_in[7];
  const float* b2 = (const float*)d_in[8];
  const float* Wl1 = (const float*)d_in[9];
  const float* bl1 = (const float*)d_in[10];
  const float* Wr1 = (const float*)d_in[11];
  const float* Wl2 = (const float*)d_in[12];
  const float* bl2 = (const float*)d_in[13];
  const float* Wr2 = (const float*)d_in[14];
  const float* Wl3 = (const float*)d_in[15];
  const float* bl3 = (const float*)d_in[16];
  const float* Wr3 = (const float*)d_in[17];
  const float* W3 = (const float*)d_in[18];
  const float* b3 = (const float*)d_in[19];

  char* base = (char*)d_ws;
  size_t off = 0;
  auto alloc = [&](size_t bytes) -> void* {
    void* r = base + off;
    off += (bytes + 255) & ~(size_t)255;
    return r;
  };

  unsigned short* Xs = (unsigned short*)alloc((size_t)2 * M_PAD * F_IN * 2);   // [Xa; Xc]
  unsigned short* AP = (unsigned short*)alloc((size_t)2 * M_PAD * 512 * 2);    // [AP; CR]
  unsigned short* CR = AP + (size_t)M_PAD * 512;
  unsigned short* h1bf = (unsigned short*)alloc((size_t)M_PAD * HID * 2);
  unsigned short* HR2 = (unsigned short*)alloc((size_t)M_PAD * HID * 2);
  unsigned short* h2bf = (unsigned short*)alloc((size_t)M_PAD * HID * 2);
  unsigned short* mean3bf = (unsigned short*)alloc((size_t)M_PAD * HID * 2);
  unsigned short* h3bf = (unsigned short*)alloc((size_t)M_PAD * HID * 2);
  unsigned short* W1bf = (unsigned short*)alloc((size_t)F_IN * PROJ * 2);
  unsigned short* W2bf = (unsigned short*)alloc((size_t)F_IN * PROJ * 2);
  unsigned short* WlT = (unsigned short*)alloc((size_t)512 * PROJ * 2);   // [Wl1^T; Wl2^T]
  unsigned short* Wr1T = (unsigned short*)alloc((size_t)HID * PROJ * 2); // contiguous after WlT
  unsigned short* F12T = (unsigned short*)alloc((size_t)512 * F_IN * 2);  // fused [512][768]
  unsigned short* GT = (unsigned short*)alloc((size_t)512 * F_IN * 2);    // contiguous after F12T
  unsigned short* Wr2T = (unsigned short*)alloc((size_t)HID * HID * 2);
  unsigned short* Wl3T = (unsigned short*)alloc((size_t)HID * HID * 2);
  unsigned short* W3T = (unsigned short*)alloc((size_t)OUTD * HID * 2);
  int* ints_base = (int*)alloc((size_t)6 * N_NODES * 4);
  float* gb1 = (float*)alloc(HID * 4);   // contiguous after ints_base (all sizes 256B-rounded)
  float* gb2 = (float*)alloc(HID * 4);
  float* bv1 = (float*)alloc(HID * 4);
  int* cnt_wb = ints_base;
  int* cur_wb = ints_base + N_NODES;
  int* cnt_mb = ints_base + 2 * N_NODES;
  int* cur_mb = ints_base + 3 * N_NODES;
  int* cnt_int = ints_base + 4 * N_NODES;
  int* cur_int = ints_base + 5 * N_NODES;
  int* off_wb = (int*)alloc((size_t)(N_NODES + 1) * 4);
  int* off_mb = (int*)alloc((size_t)(N_NODES + 1) * 4);
  int* off_int = (int*)alloc((size_t)(N_NODES + 1) * 4);
  int* srcl_wb = (int*)alloc((size_t)E_WB * 4);
  int* srcl_mb = (int*)alloc((size_t)E_MB * 4);
  int* srcl_int = (int*)alloc((size_t)E_INT * 4);

  // 1. single memset: histograms/cursors + bias accumulators (contiguous)
  size_t zbytes = (size_t)((char*)bv1 + HID * 4 - (char*)ints_base);
  hipMemsetAsync(ints_base, 0, zbytes, stream);

  // 2. all weight casts/transposes + bias prep, one launch (1912 sectioned blocks)
  prep_all_kernel<<<1912, 256, 0, stream>>>(W1, W2, Wl1, Wl2, Wr1, Wr2, Wl3, Wr3, W3,
                                            b1, b2, bl1,
                                            W1bf, W2bf, WlT, Wr1T, GT + 256 * F_IN,
                                            Wr2T, Wl3T, W3T, gb1, gb2, bv1);

  // 3. node-feature cast (stacked article+community), zero-padded rows
  cast_nodes_kernel<<<2 * M_PAD * 96 / 256, 256, 0, stream>>>(article_x, community_x, Xs);

  // 4. CSR build
  const int etot = E_WB + E_MB + E_INT;
  count_all_kernel<<<(etot + 255) / 256, 256, 0, stream>>>(e_wb + E_WB, e_mb + E_MB, e_int + E_INT,
                                                           cnt_wb, cnt_mb, cnt_int);
  scan3_kernel<<<3, 1024, 0, stream>>>(cnt_wb, cnt_mb, cnt_int, off_wb, off_mb, off_int);
  fill_all_kernel<<<(etot + 255) / 256, 256, 0, stream>>>(e_wb, e_mb, e_int, off_wb, off_mb, off_int,
                                                          cur_wb, cur_mb, cur_int,
                                                          srcl_wb, srcl_mb, srcl_int);

  // 5. fused weights via MFMA, stacked: rows 0-511 F12T = WlT@W1bf^T, rows 512-767 GT[0:256] = Wr1T@W2bf^T
  gemm_bt_kernel<0><<<6 * 6, 256, 0, stream>>>(WlT, W1bf, W2bf, 4, F12T, PROJ, F_IN,
                                               BIGM, F_IN, nullptr, nullptr, 0);

  // 6. stacked big projection: [AP; CR] = [Xa; Xc] @ [F12T | GT]^T
  gemm_bt_kernel<0><<<2 * MT_ * 4, 256, 0, stream>>>(Xs, F12T, GT, MT_, AP, F_IN, 512,
                                                     M_PAD, N_NODES, nullptr, nullptr, 0);

  // 7. conv1: h1 = relu(mean_wb(AP1) + [deg>0]*gb1 + (bl1 + b2@Wr1) + CR1)
  agg_kernel<0><<<M_PAD / 4, 256, 0, stream>>>(AP, 512, off_wb, srcl_wb, gb1, bv1, CR, 512, h1bf);

  // 8. conv2: HR2 = h1 @ Wr2 ; h2 = relu(mean_mb(AP2) + [deg>0]*gb2 + bl2 + HR2)
  gemm_bt_kernel<0><<<MT_ * 2, 256, 0, stream>>>(h1bf, Wr2T, nullptr, BIGM, HR2, HID, HID,
                                                 BIGM, N_NODES, nullptr, nullptr, 0);
  agg_kernel<1><<<M_PAD / 4, 256, 0, stream>>>(AP + 256, 512, off_mb, srcl_mb, gb2, bl2, HR2, 256, h2bf);

  // 9. conv3: mean3 = mean_int(h2) ; h3 = relu(mean3 @ Wl3 + bl3 + CR3)
  agg_kernel<2><<<M_PAD / 4, 256, 0, stream>>>(h2bf, 256, off_int, srcl_int, nullptr, nullptr,
                                               nullptr, 0, mean3bf);
  gemm_bt_kernel<1><<<MT_ * 2, 256, 0, stream>>>(mean3bf, Wl3T, nullptr, BIGM, h3bf, HID, HID,
                                                 BIGM, N_NODES, bl3, CR + 256, 512);

  // 10. out = h3 @ W3 + b3 (fp32)
  gemm_bt_kernel<2><<<MT_, 256, 0, stream>>>(h3bf, W3T, nullptr, BIGM, d_out, HID, OUTD,
                                             BIGM, N_NODES, b3, nullptr, 0);

  (void)in_sizes; (void)n_in; (void)out_size; (void)ws_size;
}

// Round 4
// 886.706 us; speedup vs baseline: 1.2989x; 1.0246x over previous
//
#include <hip/hip_runtime.h>
#include <hip/hip_bf16.h>

#define N_NODES 50000
#define M_PAD   50048   /* 391 * 128 */
#define MT_     391
#define F_IN    768
#define PROJ    1024
#define HID     256
#define OUTD    128
#define E_WB    200000
#define E_MB    200000
#define E_INT   500000
#define BIGM    (1 << 30)

typedef float f32x4 __attribute__((ext_vector_type(4)));
typedef __bf16 bf16x8 __attribute__((ext_vector_type(8)));

__device__ __forceinline__ float bf2f(unsigned short u) {
  union { unsigned int i; float f; } x; x.i = ((unsigned int)u) << 16; return x.f;
}
__device__ __forceinline__ unsigned short f2bf(float f) {
  union { float f; unsigned int i; } x; x.f = f;
  unsigned int r = x.i + 0x7fff + ((x.i >> 16) & 1);
  return (unsigned short)(r >> 16);
}

// async global->LDS, 16B per lane; lds dest is wave-uniform base (+lane*16 implicit)
__device__ __forceinline__ void gl_lds16(const void* g, void* l) {
  __builtin_amdgcn_global_load_lds((const __attribute__((address_space(1))) void*)g,
                                   (__attribute__((address_space(3))) void*)l, 16, 0, 0);
}

// ---------------- merged weight-prep kernel (sectioned) ----------------
__device__ __forceinline__ void dev_cast8(const float* __restrict__ src,
                                          unsigned short* __restrict__ dst, int blk) {
  int i = blk * 256 + threadIdx.x;     // one 8-elem chunk
  const float4* s4 = (const float4*)src;
  float4 a = s4[(long long)i * 2], b = s4[(long long)i * 2 + 1];
  uint4 o;
  o.x = (unsigned int)f2bf(a.x) | ((unsigned int)f2bf(a.y) << 16);
  o.y = (unsigned int)f2bf(a.z) | ((unsigned int)f2bf(a.w) << 16);
  o.z = (unsigned int)f2bf(b.x) | ((unsigned int)f2bf(b.y) << 16);
  o.w = (unsigned int)f2bf(b.z) | ((unsigned int)f2bf(b.w) << 16);
  ((uint4*)dst)[i] = o;
}

__device__ __forceinline__ void dev_tcast(const float* __restrict__ src,
                                          unsigned short* __restrict__ dst,
                                          int R, int C, int blk, float (*tile)[33]) {
  int bx = blk % (C / 32), by = blk / (C / 32);
  int tx = threadIdx.x & 31, ty = threadIdx.x >> 5;   // 32 x 8
  int x = bx * 32 + tx, y0 = by * 32;
  for (int i = ty; i < 32; i += 8) tile[i][tx] = src[(long long)(y0 + i) * C + x];
  __syncthreads();
  int xo = by * 32 + tx, yo0 = bx * 32;
  for (int i = ty; i < 32; i += 8) dst[(long long)(yo0 + i) * R + xo] = f2bf(tile[tx][i]);
}

__global__ void prep_all_kernel(const float* __restrict__ W1, const float* __restrict__ W2,
                                const float* __restrict__ Wl1, const float* __restrict__ Wl2,
                                const float* __restrict__ Wr1, const float* __restrict__ Wr2,
                                const float* __restrict__ Wl3, const float* __restrict__ Wr3,
                                const float* __restrict__ W3,
                                const float* __restrict__ b1, const float* __restrict__ b2,
                                const float* __restrict__ bl1,
                                unsigned short* __restrict__ W1bf, unsigned short* __restrict__ W2bf,
                                unsigned short* __restrict__ WlT, unsigned short* __restrict__ Wr1T,
                                unsigned short* __restrict__ GT_wr3, unsigned short* __restrict__ Wr2T,
                                unsigned short* __restrict__ Wl3T, unsigned short* __restrict__ W3T,
                                float* __restrict__ gb1, float* __restrict__ gb2,
                                float* __restrict__ bv1) {
  __shared__ float tile[32][33];
  int b = blockIdx.x;
  if (b < 384) { dev_cast8(W1, W1bf, b); return; }
  b -= 384;
  if (b < 384) { dev_cast8(W2, W2bf, b); return; }
  b -= 384;
  if (b < 256) { dev_tcast(Wl1, WlT, PROJ, HID, b, tile); return; }
  b -= 256;
  if (b < 256) { dev_tcast(Wl2, WlT + 256 * PROJ, PROJ, HID, b, tile); return; }
  b -= 256;
  if (b < 256) { dev_tcast(Wr1, Wr1T, PROJ, HID, b, tile); return; }
  b -= 256;
  if (b < 192) { dev_tcast(Wr3, GT_wr3, F_IN, HID, b, tile); return; }
  b -= 192;
  if (b < 64) { dev_tcast(Wr2, Wr2T, HID, HID, b, tile); return; }
  b -= 64;
  if (b < 64) { dev_tcast(Wl3, Wl3T, HID, HID, b, tile); return; }
  b -= 64;
  if (b < 32) { dev_tcast(W3, W3T, HID, OUTD, b, tile); return; }
  b -= 32;
  // bias_prep: 24 blocks = out(3) x pchunk(8); outputs pre-zeroed
  int j = threadIdx.x;
  int out = b >> 3, pg = b & 7;
  const float* vb = (out == 2) ? b2 : b1;
  const float* W = (out == 0) ? Wl1 : (out == 1 ? Wl2 : Wr1);
  float s = 0.f;
  int p0 = pg * 128;
#pragma unroll 4
  for (int p = p0; p < p0 + 128; ++p) s += vb[p] * W[p * HID + j];
  if (out == 2 && pg == 0) s += bl1[j];
  float* dst = (out == 0) ? gb1 : (out == 1 ? gb2 : bv1);
  atomicAdd(&dst[j], s);
}

// stacked node-feature cast: rows [0,M_PAD) from article, [M_PAD,2*M_PAD) from community
__global__ void cast_nodes_kernel(const float* __restrict__ ax, const float* __restrict__ cx,
                                  unsigned short* __restrict__ dst) {
  int i = blockIdx.x * 256 + threadIdx.x;            // 8-elem chunk, 96 per row
  int row = i / 96, c8 = i % 96;
  const float* src = ax;
  int vrow = row;
  if (row >= M_PAD) { src = cx; vrow = row - M_PAD; }
  uint4 o;
  if (vrow < N_NODES) {
    const float4* s4 = (const float4*)src;
    long long base = (long long)vrow * 192 + c8 * 2;
    float4 a = s4[base], bq = s4[base + 1];
    o.x = (unsigned int)f2bf(a.x) | ((unsigned int)f2bf(a.y) << 16);
    o.y = (unsigned int)f2bf(a.z) | ((unsigned int)f2bf(a.w) << 16);
    o.z = (unsigned int)f2bf(bq.x) | ((unsigned int)f2bf(bq.y) << 16);
    o.w = (unsigned int)f2bf(bq.z) | ((unsigned int)f2bf(bq.w) << 16);
  } else {
    o.x = o.y = o.z = o.w = 0u;
  }
  ((uint4*)dst)[i] = o;
}

// ---------------- CSR build ----------------
__global__ void count_all_kernel(const int* __restrict__ dwb, const int* __restrict__ dmb,
                                 const int* __restrict__ dint,
                                 int* __restrict__ cwb, int* __restrict__ cmb,
                                 int* __restrict__ cint) {
  int i = blockIdx.x * blockDim.x + threadIdx.x;
  const int total = E_WB + E_MB + E_INT;
  if (i >= total) return;
  if (i < E_WB) atomicAdd(&cwb[dwb[i]], 1);
  else if (i < E_WB + E_MB) atomicAdd(&cmb[dmb[i - E_WB]], 1);
  else atomicAdd(&cint[dint[i - E_WB - E_MB]], 1);
}

__global__ void scan3_kernel(const int* __restrict__ c0, const int* __restrict__ c1,
                             const int* __restrict__ c2,
                             int* __restrict__ o0, int* __restrict__ o1, int* __restrict__ o2) {
  const int* cnt = blockIdx.x == 0 ? c0 : (blockIdx.x == 1 ? c1 : c2);
  int* off = blockIdx.x == 0 ? o0 : (blockIdx.x == 1 ? o1 : o2);
  const int n = N_NODES;
  __shared__ int part[1024];
  int t = threadIdx.x;
  const int chunk = (n + 1023) / 1024;
  int lo = t * chunk, hi = lo + chunk; if (hi > n) hi = n; if (lo > n) lo = n;
  int s = 0;
  for (int i = lo; i < hi; ++i) s += cnt[i];
  part[t] = s; __syncthreads();
  for (int d = 1; d < 1024; d <<= 1) {
    int v = part[t];
    if (t >= d) v += part[t - d];
    __syncthreads();
    part[t] = v;
    __syncthreads();
  }
  int run = (t == 0) ? 0 : part[t - 1];
  for (int i = lo; i < hi; ++i) { off[i] = run; run += cnt[i]; }
  if (t == 1023) off[n] = part[1023];
}

__global__ void fill_all_kernel(const int* __restrict__ ewb, const int* __restrict__ emb,
                                const int* __restrict__ eint,
                                const int* __restrict__ owb, const int* __restrict__ omb,
                                const int* __restrict__ oint,
                                int* __restrict__ curwb, int* __restrict__ curmb,
                                int* __restrict__ curint,
                                int* __restrict__ swb, int* __restrict__ smb,
                                int* __restrict__ sint) {
  int i = blockIdx.x * blockDim.x + threadIdx.x;
  const int total = E_WB + E_MB + E_INT;
  if (i >= total) return;
  if (i < E_WB) {
    int s = ewb[i], d = ewb[E_WB + i];
    int p = atomicAdd(&curwb[d], 1);
    swb[owb[d] + p] = s;
  } else if (i < E_WB + E_MB) {
    int e = i - E_WB;
    int s = emb[e], d = emb[E_MB + e];
    int p = atomicAdd(&curmb[d], 1);
    smb[omb[d] + p] = s;
  } else {
    int e = i - E_WB - E_MB;
    int s = eint[e], d = eint[E_INT + e];
    int p = atomicAdd(&curint[d], 1);
    sint[oint[d] + p] = s;
  }
}

// ---------------- GEMM: C[M][N] = A[M][K](bf16) * BT[N][K](bf16)^T ----------------
// BK=64 K-loop, async global_load_lds staging, XCD-aware tile swizzle, LDS XOR swizzle.
// BT = (mt < mt_split) ? BT0 : BT1 — lets two stacked GEMMs share one launch.
// Store-row validity: vr = (R >= Mhalf ? R - Mhalf : R) < Mvalid.
// EPI 0: bf16.  EPI 1: relu(acc + bias[c] + bf2f(addm)) bf16.  EPI 2: acc + bias[c] fp32.
template <int EPI>
__global__ void __launch_bounds__(256, 4)
gemm_bt_kernel(const unsigned short* __restrict__ A, const unsigned short* __restrict__ BT0,
               const unsigned short* __restrict__ BT1, int mt_split,
               void* __restrict__ Cv, int K, int N, int Mhalf, int Mvalid,
               const float* __restrict__ bias, const unsigned short* __restrict__ addm,
               int addm_stride) {
  __shared__ __align__(16) unsigned short lA[2 * 4096];
  __shared__ __align__(16) unsigned short lB[2 * 4096];
  const int tid = threadIdx.x;
  const int lane = tid & 63;
  const int wave = tid >> 6;
  const int NT = N >> 7;

  // XCD-aware swizzle (assumes round-robin blockIdx%8 -> XCD): all NT n-tiles of
  // one m-stripe land on the same XCD so the A-stripe is fetched into one L2 only.
  int mt, nt;
  {
    const int G = NT << 3;
    const int main_count = ((int)gridDim.x / G) * G;
    if ((int)blockIdx.x < main_count) {
      int j = blockIdx.x >> 3;
      mt = (j / NT) * 8 + (blockIdx.x & 7);
      nt = j % NT;
    } else {
      int idx = blockIdx.x - main_count;
      mt = (main_count / G) * 8 + idx / NT;
      nt = idx % NT;
    }
  }
  const int m0 = mt * 128, n0 = nt * 128;
  const int wm = (wave & 1) * 64, wn = (wave >> 1) * 64;
  const unsigned short* BT = (mt < mt_split) ? BT0 : BT1;

  f32x4 acc[4][4];
#pragma unroll
  for (int i = 0; i < 4; ++i)
#pragma unroll
    for (int j = 0; j < 4; ++j)
#pragma unroll
      for (int r = 0; r < 4; ++r) acc[i][j][r] = 0.f;

  const int r0 = tid >> 2;              // LDS row this lane stages (tid*16B)
  // XOR bank swizzle: LDS slot (tid&3) holds global k-chunk (tid&3)^((tid>>3)&3)
  const int c0 = (((tid & 3) ^ ((tid >> 3) & 3)) * 8);
  const uint4* A4 = (const uint4*)A;
  const uint4* B4 = (const uint4*)BT;
  const int K8 = K >> 3;
  const int mrow = lane & 15, kq = lane >> 4;

  for (int kt = 0; kt < K; kt += 64) {
    __syncthreads();   // previous iteration's LDS readers done
#pragma unroll
    for (int s = 0; s < 2; ++s) {
      const int kc = (kt + s * 32 + c0) >> 3;
      unsigned short* lAw = &lA[s * 4096 + wave * 512];
      unsigned short* lBw = &lB[s * 4096 + wave * 512];
      gl_lds16(&A4[(long long)(m0 + r0) * K8 + kc], lAw);
      gl_lds16(&A4[(long long)(m0 + 64 + r0) * K8 + kc], lAw + 2048);
      gl_lds16(&B4[(long long)(n0 + r0) * K8 + kc], lBw);
      gl_lds16(&B4[(long long)(n0 + 64 + r0) * K8 + kc], lBw + 2048);
    }
    __syncthreads();   // drains vmcnt -> staged data visible
#pragma unroll
    for (int s = 0; s < 2; ++s) {
      bf16x8 af[4], bfr[4];
#pragma unroll
      for (int i = 0; i < 4; ++i) {
        int Ra = wm + i * 16 + mrow;
        af[i] = *(const bf16x8*)&lA[s * 4096 + Ra * 32 + ((kq ^ ((Ra >> 1) & 3)) * 8)];
      }
#pragma unroll
      for (int j = 0; j < 4; ++j) {
        int Rb = wn + j * 16 + mrow;
        bfr[j] = *(const bf16x8*)&lB[s * 4096 + Rb * 32 + ((kq ^ ((Rb >> 1) & 3)) * 8)];
      }
#pragma unroll
      for (int i = 0; i < 4; ++i)
#pragma unroll
        for (int j = 0; j < 4; ++j)
          acc[i][j] = __builtin_amdgcn_mfma_f32_16x16x32_bf16(af[i], bfr[j], acc[i][j], 0, 0, 0);
    }
  }

  const int col_l = lane & 15, rq = lane >> 4;
#pragma unroll
  for (int i = 0; i < 4; ++i) {
#pragma unroll
    for (int j = 0; j < 4; ++j) {
#pragma unroll
      for (int r = 0; r < 4; ++r) {
        int R = m0 + wm + i * 16 + rq * 4 + r;
        int Cc = n0 + wn + j * 16 + col_l;
        int vr = (R >= Mhalf) ? R - Mhalf : R;
        if (vr < Mvalid) {
          float v = acc[i][j][r];
          if constexpr (EPI == 0) {
            ((unsigned short*)Cv)[(long long)R * N + Cc] = f2bf(v);
          } else if constexpr (EPI == 1) {
            v += bias[Cc] + bf2f(addm[(long long)R * addm_stride + Cc]);
            v = v > 0.f ? v : 0.f;
            ((unsigned short*)Cv)[(long long)R * N + Cc] = f2bf(v);
          } else {
            ((float*)Cv)[(long long)R * N + Cc] = v + bias[Cc];
          }
        }
      }
    }
  }
}

// ---------------- aggregation: 4 waves/block, one wave per dst row ----------------
template <int MODE>
__global__ void agg_kernel(const unsigned short* __restrict__ S, int s_stride,
                           const int* __restrict__ off, const int* __restrict__ srcl,
                           const float* __restrict__ gb, const float* __restrict__ bvec,
                           const unsigned short* __restrict__ addm, int a_stride,
                           unsigned short* __restrict__ out) {
  int d = blockIdx.x * 4 + (threadIdx.x >> 6);
  int c = (threadIdx.x & 63) * 4;
  if (d >= N_NODES) {
    ushort4 z; z.x = z.y = z.z = z.w = 0;
    *(ushort4*)&out[(long long)d * HID + c] = z;
    return;
  }
  int lo = off[d], hi = off[d + 1];
  float s0 = 0.f, s1 = 0.f, s2 = 0.f, s3 = 0.f;
  for (int i = lo; i < hi; ++i) {
    int sidx = srcl[i];
    uint2 v = *(const uint2*)&S[(long long)sidx * s_stride + c];
    s0 += bf2f((unsigned short)(v.x & 0xffff));
    s1 += bf2f((unsigned short)(v.x >> 16));
    s2 += bf2f((unsigned short)(v.y & 0xffff));
    s3 += bf2f((unsigned short)(v.y >> 16));
  }
  int deg = hi - lo;
  float inv = deg > 0 ? 1.f / (float)deg : 0.f;
  float v0 = s0 * inv, v1 = s1 * inv, v2 = s2 * inv, v3 = s3 * inv;
  if constexpr (MODE != 2) {
    float g = deg > 0 ? 1.f : 0.f;
    uint2 am = *(const uint2*)&addm[(long long)d * a_stride + c];
    v0 += g * gb[c] + bvec[c] + bf2f((unsigned short)(am.x & 0xffff));
    v1 += g * gb[c + 1] + bvec[c + 1] + bf2f((unsigned short)(am.x >> 16));
    v2 += g * gb[c + 2] + bvec[c + 2] + bf2f((unsigned short)(am.y & 0xffff));
    v3 += g * gb[c + 3] + bvec[c + 3] + bf2f((unsigned short)(am.y >> 16));
    v0 = fmaxf(v0, 0.f); v1 = fmaxf(v1, 0.f); v2 = fmaxf(v2, 0.f); v3 = fmaxf(v3, 0.f);
  }
  ushort4 o;
  o.x = f2bf(v0); o.y = f2bf(v1); o.z = f2bf(v2); o.w = f2bf(v3);
  *(ushort4*)&out[(long long)d * HID + c] = o;
}

extern "C" void kernel_launch(void* const* d_in, const int* in_sizes, int n_in,
                              void* d_out, int out_size, void* d_ws, size_t ws_size,
                              hipStream_t stream) {
  const float* article_x = (const float*)d_in[0];
  const float* community_x = (const float*)d_in[1];
  const int* e_wb = (const int*)d_in[2];
  const int* e_mb = (const int*)d_in[3];
  const int* e_int = (const int*)d_in[4];
  const float* W1 = (const float*)d_in[5];
  const float* b1 = (const float*)d_in[6];
  const float* W2 = (const float*)d_in[7];
  const float* b2 = (const float*)d_in[8];
  const float* Wl1 = (const float*)d_in[9];
  const float* bl1 = (const float*)d_in[10];
  const float* Wr1 = (const float*)d_in[11];
  const float* Wl2 = (const float*)d_in[12];
  const float* bl2 = (const float*)d_in[13];
  const float* Wr2 = (const float*)d_in[14];
  const float* Wl3 = (const float*)d_in[15];
  const float* bl3 = (const float*)d_in[16];
  const float* Wr3 = (const float*)d_in[17];
  const float* W3 = (const float*)d_in[18];
  const float* b3 = (const float*)d_in[19];

  char* base = (char*)d_ws;
  size_t off = 0;
  auto alloc = [&](size_t bytes) -> void* {
    void* r = base + off;
    off += (bytes + 255) & ~(size_t)255;
    return r;
  };

  unsigned short* Xs = (unsigned short*)alloc((size_t)2 * M_PAD * F_IN * 2);   // [Xa; Xc]
  unsigned short* AP = (unsigned short*)alloc((size_t)2 * M_PAD * 512 * 2);    // [AP; CR]
  unsigned short* CR = AP + (size_t)M_PAD * 512;
  unsigned short* h1bf = (unsigned short*)alloc((size_t)M_PAD * HID * 2);
  unsigned short* HR2 = (unsigned short*)alloc((size_t)M_PAD * HID * 2);
  unsigned short* h2bf = (unsigned short*)alloc((size_t)M_PAD * HID * 2);
  unsigned short* mean3bf = (unsigned short*)alloc((size_t)M_PAD * HID * 2);
  unsigned short* h3bf = (unsigned short*)alloc((size_t)M_PAD * HID * 2);
  unsigned short* W1bf = (unsigned short*)alloc((size_t)F_IN * PROJ * 2);
  unsigned short* W2bf = (unsigned short*)alloc((size_t)F_IN * PROJ * 2);
  unsigned short* WlT = (unsigned short*)alloc((size_t)512 * PROJ * 2);   // [Wl1^T; Wl2^T]
  unsigned short* Wr1T = (unsigned short*)alloc((size_t)HID * PROJ * 2);
  unsigned short* F12T = (unsigned short*)alloc((size_t)512 * F_IN * 2);  // fused [512][768]
  unsigned short* GT = (unsigned short*)alloc((size_t)512 * F_IN * 2);    // contiguous after F12T
  unsigned short* Wr2T = (unsigned short*)alloc((size_t)HID * HID * 2);
  unsigned short* Wl3T = (unsigned short*)alloc((size_t)HID * HID * 2);
  unsigned short* W3T = (unsigned short*)alloc((size_t)OUTD * HID * 2);
  int* ints_base = (int*)alloc((size_t)6 * N_NODES * 4);
  float* gb1 = (float*)alloc(HID * 4);   // contiguous after ints_base (all sizes 256B-rounded)
  float* gb2 = (float*)alloc(HID * 4);
  float* bv1 = (float*)alloc(HID * 4);
  int* cnt_wb = ints_base;
  int* cur_wb = ints_base + N_NODES;
  int* cnt_mb = ints_base + 2 * N_NODES;
  int* cur_mb = ints_base + 3 * N_NODES;
  int* cnt_int = ints_base + 4 * N_NODES;
  int* cur_int = ints_base + 5 * N_NODES;
  int* off_wb = (int*)alloc((size_t)(N_NODES + 1) * 4);
  int* off_mb = (int*)alloc((size_t)(N_NODES + 1) * 4);
  int* off_int = (int*)alloc((size_t)(N_NODES + 1) * 4);
  int* srcl_wb = (int*)alloc((size_t)E_WB * 4);
  int* srcl_mb = (int*)alloc((size_t)E_MB * 4);
  int* srcl_int = (int*)alloc((size_t)E_INT * 4);

  // 1. single memset: histograms/cursors + bias accumulators (contiguous)
  size_t zbytes = (size_t)((char*)bv1 + HID * 4 - (char*)ints_base);
  hipMemsetAsync(ints_base, 0, zbytes, stream);

  // 2. all weight casts/transposes + bias prep, one launch (1912 sectioned blocks)
  prep_all_kernel<<<1912, 256, 0, stream>>>(W1, W2, Wl1, Wl2, Wr1, Wr2, Wl3, Wr3, W3,
                                            b1, b2, bl1,
                                            W1bf, W2bf, WlT, Wr1T, GT + 256 * F_IN,
                                            Wr2T, Wl3T, W3T, gb1, gb2, bv1);

  // 3. node-feature cast (stacked article+community), zero-padded rows
  cast_nodes_kernel<<<2 * M_PAD * 96 / 256, 256, 0, stream>>>(article_x, community_x, Xs);

  // 4. CSR build
  const int etot = E_WB + E_MB + E_INT;
  count_all_kernel<<<(etot + 255) / 256, 256, 0, stream>>>(e_wb + E_WB, e_mb + E_MB, e_int + E_INT,
                                                           cnt_wb, cnt_mb, cnt_int);
  scan3_kernel<<<3, 1024, 0, stream>>>(cnt_wb, cnt_mb, cnt_int, off_wb, off_mb, off_int);
  fill_all_kernel<<<(etot + 255) / 256, 256, 0, stream>>>(e_wb, e_mb, e_int, off_wb, off_mb, off_int,
                                                          cur_wb, cur_mb, cur_int,
                                                          srcl_wb, srcl_mb, srcl_int);

  // 5. fused weights via MFMA, stacked: rows 0-511 F12T = WlT@W1bf^T, rows 512-767 GT[0:256] = Wr1T@W2bf^T
  gemm_bt_kernel<0><<<6 * 6, 256, 0, stream>>>(WlT, W1bf, W2bf, 4, F12T, PROJ, F_IN,
                                               BIGM, F_IN, nullptr, nullptr, 0);

  // 6. stacked big projection: [AP; CR] = [Xa; Xc] @ [F12T | GT]^T
  gemm_bt_kernel<0><<<2 * MT_ * 4, 256, 0, stream>>>(Xs, F12T, GT, MT_, AP, F_IN, 512,
                                                     M_PAD, N_NODES, nullptr, nullptr, 0);

  // 7. conv1: h1 = relu(mean_wb(AP1) + [deg>0]*gb1 + (bl1 + b2@Wr1) + CR1)
  agg_kernel<0><<<M_PAD / 4, 256, 0, stream>>>(AP, 512, off_wb, srcl_wb, gb1, bv1, CR, 512, h1bf);

  // 8. conv2: HR2 = h1 @ Wr2 ; h2 = relu(mean_mb(AP2) + [deg>0]*gb2 + bl2 + HR2)
  gemm_bt_kernel<0><<<MT_ * 2, 256, 0, stream>>>(h1bf, Wr2T, nullptr, BIGM, HR2, HID, HID,
                                                 BIGM, N_NODES, nullptr, nullptr, 0);
  agg_kernel<1><<<M_PAD / 4, 256, 0, stream>>>(AP + 256, 512, off_mb, srcl_mb, gb2, bl2, HR2, 256, h2bf);

  // 9. conv3: mean3 = mean_int(h2) ; h3 = relu(mean3 @ Wl3 + bl3 + CR3)
  agg_kernel<2><<<M_PAD / 4, 256, 0, stream>>>(h2bf, 256, off_int, srcl_int, nullptr, nullptr,
                                               nullptr, 0, mean3bf);
  gemm_bt_kernel<1><<<MT_ * 2, 256, 0, stream>>>(mean3bf, Wl3T, nullptr, BIGM, h3bf, HID, HID,
                                                 BIGM, N_NODES, bl3, CR + 256, 512);

  // 10. out = h3 @ W3 + b3 (fp32)
  gemm_bt_kernel<2><<<MT_, 256, 0, stream>>>(h3bf, W3T, nullptr, BIGM, d_out, HID, OUTD,
                                             BIGM, N_NODES, b3, nullptr, 0);

  (void)in_sizes; (void)n_in; (void)out_size; (void)ws_size;
}